// Round 18
// baseline (166.109 us; speedup 1.0000x reference)
//
#include <hip/hip_runtime.h>
#include <cstdint>
#include <cstddef>

#define B_TOT   16384
#define F_DIM   1024
#define P_TOT   1024
#define K_IN    9
#define W_H     10
#define TB      128     // batch rows per block (2 per lane)
#define THREADS 1024    // 16 waves
#define NWAVE   16
#define PGRP    2       // patch groups (P split across blocks)
#define PPB     (P_TOT / PGRP)   // 512 patches per block
#define LSTR    1028    // LDS x row stride in BYTES (fp8); conflict-free gathers

// quantized per-patch record, REC_DW=96 dwords, two 16B-aligned halves:
// V-half (vector-loaded, needed early):
//   [0..8]=idx  [9]=s1*C  [10..19]=b1*C  [20..42]=W1q (45 fp8-pairs)  [43..47]=pad
// S-half (scalar-loaded, needed late):
//   [48]=s2  [49]=s3*wl  [50]=b3*wl  [51]=pad  [52..61]=b2
//   [62..86]=W2q (50 pairs)  [87..89]=W3q (5 pairs)  [90..95]=pad
#define REC_DW   96
#define TANH_C   2.8853900817779268f    // 2*log2(e)
#define F8_MAX   448.0f                 // e4m3fn max finite

typedef float f32x2 __attribute__((ext_vector_type(2)));

__device__ __forceinline__ float fast_exp2(float x) {
#if __has_builtin(__builtin_amdgcn_exp2f)
    return __builtin_amdgcn_exp2f(x);
#else
    return exp2f(x);
#endif
}
__device__ __forceinline__ float fast_rcp(float x) {
#if __has_builtin(__builtin_amdgcn_rcpf)
    return __builtin_amdgcn_rcpf(x);
#else
    return 1.0f / x;
#endif
}
// z is already 2*log2e*(W.x+b); tanh = 1 - 2/(exp2(z)+1); robust at +-inf
__device__ __forceinline__ float tanh_pre(float z) {
    float t = fast_exp2(z);
    return fmaf(-2.0f, fast_rcp(t + 1.0f), 1.0f);
}
__device__ __forceinline__ f32x2 pkfma(f32x2 a, f32x2 b, f32x2 c) {
#if __has_builtin(__builtin_elementwise_fma)
    return __builtin_elementwise_fma(a, b, c);   // -> v_pk_fma_f32
#else
    return f32x2{fmaf(a[0], b[0], c[0]), fmaf(a[1], b[1], c[1])};
#endif
}
// unpack fp8 pair from halfword 0 / 1 of dword u (constant selectors only)
__device__ __forceinline__ f32x2 unpk8_w0(uint32_t u) {
#if __has_builtin(__builtin_amdgcn_cvt_pk_f32_fp8)
    auto v = __builtin_amdgcn_cvt_pk_f32_fp8((int)u, false);
    return f32x2{v[0], v[1]};
#else
    return f32x2{__builtin_amdgcn_cvt_f32_fp8((int)u, 0),
                 __builtin_amdgcn_cvt_f32_fp8((int)u, 1)};
#endif
}
__device__ __forceinline__ f32x2 unpk8_w1(uint32_t u) {
#if __has_builtin(__builtin_amdgcn_cvt_pk_f32_fp8)
    auto v = __builtin_amdgcn_cvt_pk_f32_fp8((int)u, true);
    return f32x2{v[0], v[1]};
#else
    return f32x2{__builtin_amdgcn_cvt_f32_fp8((int)u, 2),
                 __builtin_amdgcn_cvt_f32_fp8((int)u, 3)};
#endif
}
// word selected by unrolled loop var: folds to one call after unroll
__device__ __forceinline__ f32x2 unpk8s(uint32_t u, int word) {
    return word ? unpk8_w1(u) : unpk8_w0(u);
}
// pack two fp32 pairs -> one dword of 4 fp8 (constant word args)
__device__ __forceinline__ uint32_t pk2(float a0, float a1, float b0, float b1) {
    uint32_t u = (uint32_t)__builtin_amdgcn_cvt_pk_fp8_f32(a0, a1, 0, false);
    u = (uint32_t)__builtin_amdgcn_cvt_pk_fp8_f32(b0, b1, (int)u, true);
    return u;
}
// pick component j (constant after unroll) of a uint4 without dynamic indexing
__device__ __forceinline__ uint32_t comp4(const uint4& c, int j) {
    switch (j & 3) { case 0: return c.x; case 1: return c.y;
                     case 2: return c.z; default: return c.w; }
}
__device__ __forceinline__ uint32_t cvdw(const uint4* cv, int d) {
    return comp4(cv[d >> 2], d & 3);
}
__device__ __forceinline__ float cvf(const uint4* cv, int d) {
    return __uint_as_float(cvdw(cv, d));
}
// V-half bulk load through a laundered (vector) pointer: 11x dwordx4
__device__ __forceinline__ void ld_cv(uint4* dst, const uint32_t* recp) {
    const uint4* rv = reinterpret_cast<const uint4*>(recp);
    asm("" : "+v"(rv));
    #pragma unroll
    for (int i = 0; i < 11; ++i) dst[i] = rv[i];
}

// ---- prep: one value for record dword dw of patch p ----
__device__ __forceinline__ uint32_t rec_dword(
    int p, int dw, const int* idx,
    const float* w1, const float* b1, const float* w2, const float* b2,
    const float* w3, const float* b3, const float* wl,
    float s1, float q1, float s2, float q2, float s3, float q3)
{
    if (dw < 9)  return (uint32_t)idx[p * 9 + dw];
    if (dw == 9) return __float_as_uint(s1 * TANH_C);
    if (dw < 20) return __float_as_uint(b1[p * 10 + (dw - 10)] * TANH_C);
    if (dw < 43) {                     // W1q: pair t -> e=(t/5)*10+2*(t%5)
        const int d = dw - 20, t0 = 2 * d, t1 = t0 + 1;
        const int e0 = (t0 / 5) * 10 + 2 * (t0 % 5);
        const float a0 = w1[e0] * q1, a1 = w1[e0 + 1] * q1;
        float bq0 = 0.f, bq1 = 0.f;
        if (t1 < 45) {
            const int e1 = (t1 / 5) * 10 + 2 * (t1 % 5);
            bq0 = w1[e1] * q1; bq1 = w1[e1 + 1] * q1;
        }
        return pk2(a0, a1, bq0, bq1);
    }
    if (dw < 48) return 0;
    if (dw == 48) return __float_as_uint(s2);
    if (dw == 49) return __float_as_uint(s3 * wl[p]);
    if (dw == 50) return __float_as_uint(b3[p] * wl[p]);
    if (dw == 51) return 0;
    if (dw < 62) return __float_as_uint(b2[p * 10 + (dw - 52)]);
    if (dw < 87) {                     // W2q
        const int d = dw - 62, t0 = 2 * d, t1 = t0 + 1;
        const int e0 = (t0 / 5) * 10 + 2 * (t0 % 5);
        const int e1 = (t1 / 5) * 10 + 2 * (t1 % 5);
        return pk2(w2[e0] * q2, w2[e0 + 1] * q2, w2[e1] * q2, w2[e1 + 1] * q2);
    }
    if (dw < 90) {                     // W3q
        const int d = dw - 87, t0 = 2 * d, t1 = t0 + 1;
        const float a0 = w3[2 * t0] * q3, a1 = w3[2 * t0 + 1] * q3;
        const float bq0 = (t1 < 5) ? w3[2 * t1] * q3     : 0.f;
        const float bq1 = (t1 < 5) ? w3[2 * t1 + 1] * q3 : 0.f;
        return pk2(a0, a1, bq0, bq1);
    }
    return 0;
}

// ---- prep: quantize weights to fp8 records, 1 WAVE per patch ----
__global__ __launch_bounds__(64)
void prep_quant(const int* __restrict__ idx,
                const float* __restrict__ W1, const float* __restrict__ b1,
                const float* __restrict__ W2, const float* __restrict__ b2,
                const float* __restrict__ W3, const float* __restrict__ b3,
                const float* __restrict__ wl, uint32_t* __restrict__ ws)
{
    const int p = blockIdx.x;
    const int l = threadIdx.x;           // 0..63
    const float* w1 = W1 + p * 90;
    const float* w2 = W2 + p * 100;
    const float* w3 = W3 + p * 10;

    // wave-parallel amax (max is order-independent -> deterministic scales)
    float m1 = (l < 90) ? fabsf(w1[l]) : 0.0f;
    if (l + 64 < 90) m1 = fmaxf(m1, fabsf(w1[l + 64]));
    float m2 = fabsf(w2[l]);
    if (l + 64 < 100) m2 = fmaxf(m2, fabsf(w2[l + 64]));
    float m3 = (l < 10) ? fabsf(w3[l]) : 0.0f;
    #pragma unroll
    for (int off = 32; off > 0; off >>= 1) {
        m1 = fmaxf(m1, __shfl_xor(m1, off));
        m2 = fmaxf(m2, __shfl_xor(m2, off));
        m3 = fmaxf(m3, __shfl_xor(m3, off));
    }
    m1 = fmaxf(m1, 1e-20f); m2 = fmaxf(m2, 1e-20f); m3 = fmaxf(m3, 1e-20f);
    const float s1 = m1 / F8_MAX, q1 = F8_MAX / m1;
    const float s2 = m2 / F8_MAX, q2 = F8_MAX / m2;
    const float s3 = m3 / F8_MAX, q3 = F8_MAX / m3;

    uint32_t* r = ws + (size_t)p * REC_DW;
    r[l] = rec_dword(p, l, idx, w1, b1, w2, b2, w3, b3, wl,
                     s1, q1, s2, q2, s3, q3);
    if (l < REC_DW - 64)
        r[64 + l] = rec_dword(p, 64 + l, idx, w1, b1, w2, b2, w3, b3, wl,
                              s1, q1, s2, q2, s3, q3);
}

__global__ __launch_bounds__(THREADS, 4)
void dnn_q8(const float* __restrict__ x, const uint32_t* __restrict__ ws,
            const float* __restrict__ wl, float* __restrict__ out)
{
    extern __shared__ unsigned char xs[];        // [TB][LSTR] fp8(e4m3) x tile
    __shared__ float partial[NWAVE][TB];

    const int tid = threadIdx.x;
    const int b0  = blockIdx.x * TB;
    const int p0  = blockIdx.y * PPB;

    // ---- stage x tile (fp32 global, coalesced float4) -> fp8 LDS ----
    #pragma unroll
    for (int i = 0; i < (TB * (F_DIM / 4)) / THREADS; ++i) {   // 32 iters
        const int q   = i * THREADS + tid;
        const int row = q >> 8;
        const int c4  = q & 255;
        const float4 v = *reinterpret_cast<const float4*>(
            x + (size_t)(b0 + row) * F_DIM + (c4 << 2));
        int pk = __builtin_amdgcn_cvt_pk_fp8_f32(v.x, v.y, 0, false);
        pk     = __builtin_amdgcn_cvt_pk_fp8_f32(v.z, v.w, pk, true);
        *reinterpret_cast<uint32_t*>(xs + row * LSTR + (c4 << 2)) = (uint32_t)pk;
    }
    __syncthreads();

    const int lane = tid & 63;
    const int wave = tid >> 6;
    const unsigned char* __restrict__ row0 = xs + lane * LSTR;
    const unsigned char* __restrict__ row1 = xs + (lane + 64) * LSTR;

    float y0 = 0.0f, y1 = 0.0f;

    // software pipeline depth 1 on the V-half: preload first record
    uint4 cv[11];
    ld_cv(cv, ws + (size_t)(p0 + wave) * REC_DW);

    for (int jp = 0; jp < PPB / NWAVE; ++jp) {   // 32 iters, 1 patch/wave, 2 rows/lane
        const int p  = p0 + jp * NWAVE + wave;
        const int pu = __builtin_amdgcn_readfirstlane(p);
        // S-half: wave-uniform -> scalar s_loads issued here, consumed after
        // L1+tanh (~1000 cy later) -> latency hidden
        const uint32_t* __restrict__ recs = ws + (size_t)pu * REC_DW;
        const float*    __restrict__ rfs  = reinterpret_cast<const float*>(recs);

        // gather 9 features for both rows (conflict-free: stride 1028 B)
        float xg0[K_IN], xg1[K_IN];
        #pragma unroll
        for (int k = 0; k < K_IN; ++k) {
            const int c = (int)cvdw(cv, k);
            xg0[k] = __builtin_amdgcn_cvt_f32_fp8((int)row0[c], 0);
            xg1[k] = __builtin_amdgcn_cvt_f32_fp8((int)row1[c], 0);
        }

        // layer 1: quantized accumulate (W1q from cv), 2 rows share dequant
        f32x2 H0[5], H1[5];
        #pragma unroll
        for (int j = 0; j < 5; ++j) { H0[j] = f32x2{0.f, 0.f}; H1[j] = f32x2{0.f, 0.f}; }
        #pragma unroll
        for (int k = 0; k < K_IN; ++k) {
            const f32x2 xa = {xg0[k], xg0[k]};
            const f32x2 xb = {xg1[k], xg1[k]};
            #pragma unroll
            for (int j = 0; j < 5; ++j) {
                const int t = k * 5 + j;
                const f32x2 w = unpk8s(cvdw(cv, 20 + (t >> 1)), t & 1);
                H0[j] = pkfma(xa, w, H0[j]);
                H1[j] = pkfma(xb, w, H1[j]);
            }
        }
        const float s1c = cvf(cv, 9);
        const f32x2 s1p = {s1c, s1c};
        float h10[W_H], h11[W_H];
        #pragma unroll
        for (int j = 0; j < 5; ++j) {
            const f32x2 bj = {cvf(cv, 10 + 2 * j), cvf(cv, 11 + 2 * j)};
            const f32x2 z0 = pkfma(H0[j], s1p, bj);
            const f32x2 z1 = pkfma(H1[j], s1p, bj);
            h10[2 * j]     = tanh_pre(z0[0]);
            h10[2 * j + 1] = tanh_pre(z0[1]);
            h11[2 * j]     = tanh_pre(z1[0]);
            h11[2 * j + 1] = tanh_pre(z1[1]);
        }

        // cv is dead now: re-load it for the NEXT patch at this WAR point.
        // sched_barrier pins the loads here so L2/L3 compute (~700cy, fed by
        // the scalar S-half) hides their latency. Tail prefetch reads record
        // #1024 which exists inside ws (unused values).
        ld_cv(cv, ws + (size_t)(p + NWAVE) * REC_DW);
        __builtin_amdgcn_sched_barrier(0);

        // layer 2: quantized accumulate (W2q via scalar path)
        f32x2 G0[5], G1[5];
        #pragma unroll
        for (int j = 0; j < 5; ++j) { G0[j] = f32x2{0.f, 0.f}; G1[j] = f32x2{0.f, 0.f}; }
        #pragma unroll
        for (int w = 0; w < W_H; ++w) {
            const f32x2 ha = {h10[w], h10[w]};
            const f32x2 hb = {h11[w], h11[w]};
            #pragma unroll
            for (int j = 0; j < 5; ++j) {
                const int t = w * 5 + j;
                const f32x2 wv = unpk8s(recs[62 + (t >> 1)], t & 1);
                G0[j] = pkfma(ha, wv, G0[j]);
                G1[j] = pkfma(hb, wv, G1[j]);
            }
        }

        // O = G*s2 + b2, then layer 3 quantized dot; y += A.s3w + b3w
        const float s2v = rfs[48], s3w = rfs[49], b3w = rfs[50];
        const f32x2 s2p = {s2v, s2v};
        f32x2 A0 = {0.f, 0.f}, A1 = {0.f, 0.f};
        #pragma unroll
        for (int j = 0; j < 5; ++j) {
            const f32x2 b2j = {rfs[52 + 2 * j], rfs[53 + 2 * j]};
            const f32x2 O0  = pkfma(G0[j], s2p, b2j);
            const f32x2 O1  = pkfma(G1[j], s2p, b2j);
            const f32x2 w3v = unpk8s(recs[87 + (j >> 1)], j & 1);
            A0 = pkfma(O0, w3v, A0);
            A1 = pkfma(O1, w3v, A1);
        }
        y0 = fmaf(A0[0] + A0[1], s3w, y0) + b3w;
        y1 = fmaf(A1[0] + A1[1], s3w, y1) + b3w;
    }

    partial[wave][lane]      = y0;
    partial[wave][lane + 64] = y1;
    __syncthreads();

    // ---- block reduction over the 16 waves + outputs ----
    if (tid < TB) {
        float s = 0.0f;
        #pragma unroll
        for (int w = 0; w < NWAVE; ++w) s += partial[w][tid];
        // two pgroup blocks contribute per y element; fp32 add is commutative
        atomicAdd(&out[b0 + tid], s);
    }

    if (blockIdx.y == 0 && tid < 64) {
        // channel 2: sum(|w_last|), computed redundantly per row-block
        float sa = 0.0f;
        #pragma unroll
        for (int i = 0; i < P_TOT / 64; ++i) sa += fabsf(wl[tid + 64 * i]);
        #pragma unroll
        for (int off = 32; off > 0; off >>= 1) sa += __shfl_down(sa, off);
        sa = __shfl(sa, 0);
        out[B_TOT + b0 + tid]      = sa;
        out[B_TOT + b0 + 64 + tid] = sa;
    }
}

extern "C" void kernel_launch(void* const* d_in, const int* in_sizes, int n_in,
                              void* d_out, int out_size, void* d_ws, size_t ws_size,
                              hipStream_t stream)
{
    const float* x  = (const float*)d_in[0];
    const int*   idx= (const int*)  d_in[1];
    const float* W1 = (const float*)d_in[2];
    const float* b1 = (const float*)d_in[3];
    const float* W2 = (const float*)d_in[4];
    const float* b2 = (const float*)d_in[5];
    const float* W3 = (const float*)d_in[6];
    const float* b3 = (const float*)d_in[7];
    const float* wl = (const float*)d_in[8];
    float* out = (float*)d_out;
    uint32_t* ws = (uint32_t*)d_ws;   // need 385KB incl. tail pad; ws >= 950KB (R10)

    // zero the y channel (atomicAdd accumulates into it)
    (void)hipMemsetAsync(out, 0, B_TOT * sizeof(float), stream);

    prep_quant<<<P_TOT, 64, 0, stream>>>(idx, W1, b1, W2, b2, W3, b3, wl, ws);

    const int smem = TB * LSTR;  // 131584 B dynamic LDS (>64KB -> opt in)
    (void)hipFuncSetAttribute(reinterpret_cast<const void*>(dnn_q8),
                              hipFuncAttributeMaxDynamicSharedMemorySize, smem);

    dim3 grid(B_TOT / TB, PGRP);   // 128 x 2 = 256 blocks
    dnn_q8<<<grid, THREADS, smem, stream>>>(x, ws, wl, out);
}

// Round 21
// 109.590 us; speedup vs baseline: 1.5157x; 1.5157x over previous
//
#include <hip/hip_runtime.h>
#include <cstdint>
#include <cstddef>

#define B_TOT   16384
#define F_DIM   1024
#define P_TOT   1024
#define K_IN    9
#define W_H     10
#define TB      128     // batch rows per block (2 per lane)
#define THREADS 1024    // 16 waves
#define NWAVE   16
#define PGRP    2       // patch groups (P split across blocks)
#define PPB     (P_TOT / PGRP)   // 512 patches per block
#define LSTR    1028    // LDS x row stride in BYTES (fp8); conflict-free gathers

// record, REC_DW=64 dwords (layers 2+3 collapsed: y += c0 + sum cw[w]*r_w):
// V-half (vector-loaded, needed early):
//   [0..8]=idx  [9]=s1*C  [10..19]=b1*C  [20..42]=W1q (45 fp8-pairs)  [43..47]=pad
// S-half (scalar-loaded, needed late):
//   [48]=c0  [49]=pad  [50..59]=cw (f32)  [60..63]=pad
#define REC_DW   64
#define TANH_C   2.8853900817779268f    // 2*log2(e)
#define F8_MAX   448.0f                 // e4m3fn max finite

typedef float f32x2 __attribute__((ext_vector_type(2)));

__device__ __forceinline__ float fast_exp2(float x) {
#if __has_builtin(__builtin_amdgcn_exp2f)
    return __builtin_amdgcn_exp2f(x);
#else
    return exp2f(x);
#endif
}
__device__ __forceinline__ float fast_rcp(float x) {
#if __has_builtin(__builtin_amdgcn_rcpf)
    return __builtin_amdgcn_rcpf(x);
#else
    return 1.0f / x;
#endif
}
// r = 1/(exp2(z)+1), z = 2*log2e*(Wx+b); tanh = 1-2r folded into cw,c0
__device__ __forceinline__ float sigm_r(float z) {
    return fast_rcp(fast_exp2(z) + 1.0f);
}
__device__ __forceinline__ f32x2 pkfma(f32x2 a, f32x2 b, f32x2 c) {
#if __has_builtin(__builtin_elementwise_fma)
    return __builtin_elementwise_fma(a, b, c);   // -> v_pk_fma_f32
#else
    return f32x2{fmaf(a[0], b[0], c[0]), fmaf(a[1], b[1], c[1])};
#endif
}
// unpack fp8 pair from halfword 0 / 1 of dword u (constant selectors only)
__device__ __forceinline__ f32x2 unpk8_w0(uint32_t u) {
#if __has_builtin(__builtin_amdgcn_cvt_pk_f32_fp8)
    auto v = __builtin_amdgcn_cvt_pk_f32_fp8((int)u, false);
    return f32x2{v[0], v[1]};
#else
    return f32x2{__builtin_amdgcn_cvt_f32_fp8((int)u, 0),
                 __builtin_amdgcn_cvt_f32_fp8((int)u, 1)};
#endif
}
__device__ __forceinline__ f32x2 unpk8_w1(uint32_t u) {
#if __has_builtin(__builtin_amdgcn_cvt_pk_f32_fp8)
    auto v = __builtin_amdgcn_cvt_pk_f32_fp8((int)u, true);
    return f32x2{v[0], v[1]};
#else
    return f32x2{__builtin_amdgcn_cvt_f32_fp8((int)u, 2),
                 __builtin_amdgcn_cvt_f32_fp8((int)u, 3)};
#endif
}
__device__ __forceinline__ f32x2 unpk8s(uint32_t u, int word) {
    return word ? unpk8_w1(u) : unpk8_w0(u);
}
// pack two fp32 pairs -> one dword of 4 fp8 (constant word args)
__device__ __forceinline__ uint32_t pk2(float a0, float a1, float b0, float b1) {
    uint32_t u = (uint32_t)__builtin_amdgcn_cvt_pk_fp8_f32(a0, a1, 0, false);
    u = (uint32_t)__builtin_amdgcn_cvt_pk_fp8_f32(b0, b1, (int)u, true);
    return u;
}
// pick component j (constant after unroll) of a uint4 without dynamic indexing
__device__ __forceinline__ uint32_t comp4(const uint4& c, int j) {
    switch (j & 3) { case 0: return c.x; case 1: return c.y;
                     case 2: return c.z; default: return c.w; }
}
__device__ __forceinline__ uint32_t cvdw(const uint4* cv, int d) {
    return comp4(cv[d >> 2], d & 3);
}
__device__ __forceinline__ float cvf(const uint4* cv, int d) {
    return __uint_as_float(cvdw(cv, d));
}
// V-half bulk load through a laundered (vector) pointer: 11x dwordx4
__device__ __forceinline__ void ld_cv(uint4* dst, const uint32_t* recp) {
    const uint4* rv = reinterpret_cast<const uint4*>(recp);
    asm("" : "+v"(rv));
    #pragma unroll
    for (int i = 0; i < 11; ++i) dst[i] = rv[i];
}

// ---- prep: one value for record dword dw of patch p ----
__device__ __forceinline__ uint32_t rec_dword(
    int p, int dw, const int* idx,
    const float* w1, const float* b1, const float* w2, const float* b2,
    const float* w3, const float* b3, const float* wl,
    float s1, float q1)
{
    if (dw < 9)  return (uint32_t)idx[p * 9 + dw];
    if (dw == 9) return __float_as_uint(s1 * TANH_C);
    if (dw < 20) return __float_as_uint(b1[p * 10 + (dw - 10)] * TANH_C);
    if (dw < 43) {                     // W1q: pair t -> e=(t/5)*10+2*(t%5)
        const int d = dw - 20, t0 = 2 * d, t1 = t0 + 1;
        const int e0 = (t0 / 5) * 10 + 2 * (t0 % 5);
        const float a0 = w1[e0] * q1, a1 = w1[e0 + 1] * q1;
        float bq0 = 0.f, bq1 = 0.f;
        if (t1 < 45) {
            const int e1 = (t1 / 5) * 10 + 2 * (t1 % 5);
            bq0 = w1[e1] * q1; bq1 = w1[e1 + 1] * q1;
        }
        return pk2(a0, a1, bq0, bq1);
    }
    if (dw < 48) return 0;
    if (dw == 48) {                    // c0 = wl*(sum_w W23[w] + sum_v b2[v]w3[v] + b3)
        float bb = b3[p];
        for (int v = 0; v < 10; ++v) bb = fmaf(b2[p * 10 + v], w3[v], bb);
        float s = 0.f;
        for (int w = 0; w < 10; ++w)
            for (int v = 0; v < 10; ++v)
                s = fmaf(w2[w * 10 + v], w3[v], s);
        return __float_as_uint(wl[p] * (s + bb));
    }
    if (dw == 49) return 0;
    if (dw < 60) {                     // cw[w] = -2*wl*sum_v W2[w][v]*W3[v]
        const int w = dw - 50;
        float s = 0.f;
        for (int v = 0; v < 10; ++v) s = fmaf(w2[w * 10 + v], w3[v], s);
        return __float_as_uint(-2.0f * wl[p] * s);
    }
    return 0;
}

// ---- prep: build records, 1 WAVE per patch ----
__global__ __launch_bounds__(64)
void prep_quant(const int* __restrict__ idx,
                const float* __restrict__ W1, const float* __restrict__ b1,
                const float* __restrict__ W2, const float* __restrict__ b2,
                const float* __restrict__ W3, const float* __restrict__ b3,
                const float* __restrict__ wl, uint32_t* __restrict__ ws)
{
    const int p = blockIdx.x;
    const int l = threadIdx.x;           // 0..63
    const float* w1 = W1 + p * 90;
    const float* w2 = W2 + p * 100;
    const float* w3 = W3 + p * 10;

    // wave-parallel amax over W1 (order-independent -> deterministic scale)
    float m1 = (l < 90) ? fabsf(w1[l]) : 0.0f;
    if (l + 64 < 90) m1 = fmaxf(m1, fabsf(w1[l + 64]));
    #pragma unroll
    for (int off = 32; off > 0; off >>= 1)
        m1 = fmaxf(m1, __shfl_xor(m1, off));
    m1 = fmaxf(m1, 1e-20f);
    const float s1 = m1 / F8_MAX, q1 = F8_MAX / m1;

    ws[(size_t)p * REC_DW + l] =
        rec_dword(p, l, idx, w1, b1, w2, b2, w3, b3, wl, s1, q1);
}

__global__ __launch_bounds__(THREADS, 4)
void dnn_q8(const float* __restrict__ x, const uint32_t* __restrict__ ws,
            const float* __restrict__ wl, float* __restrict__ out)
{
    extern __shared__ unsigned char xs[];        // [TB][LSTR] fp8(e4m3) x tile
    __shared__ float partial[NWAVE][TB];

    const int tid = threadIdx.x;
    const int b0  = blockIdx.x * TB;
    const int p0  = blockIdx.y * PPB;

    // ---- stage x tile (fp32 global, coalesced float4) -> fp8 LDS ----
    #pragma unroll
    for (int i = 0; i < (TB * (F_DIM / 4)) / THREADS; ++i) {   // 32 iters
        const int q   = i * THREADS + tid;
        const int row = q >> 8;
        const int c4  = q & 255;
        const float4 v = *reinterpret_cast<const float4*>(
            x + (size_t)(b0 + row) * F_DIM + (c4 << 2));
        int pk = __builtin_amdgcn_cvt_pk_fp8_f32(v.x, v.y, 0, false);
        pk     = __builtin_amdgcn_cvt_pk_fp8_f32(v.z, v.w, pk, true);
        *reinterpret_cast<uint32_t*>(xs + row * LSTR + (c4 << 2)) = (uint32_t)pk;
    }
    __syncthreads();

    const int lane = tid & 63;
    const int wave = tid >> 6;
    const unsigned char* __restrict__ row0 = xs + lane * LSTR;
    const unsigned char* __restrict__ row1 = xs + (lane + 64) * LSTR;

    float y0 = 0.0f, y1 = 0.0f;

    for (int jp = 0; jp < PPB / NWAVE; ++jp) {   // 32 iters, 1 patch/wave, 2 rows/lane
        const int p  = p0 + jp * NWAVE + wave;
        const int pu = __builtin_amdgcn_readfirstlane(p);
        // S-half: wave-uniform scalar s_loads (c0, cw) consumed after L1+tanh
        const float* __restrict__ rfs =
            reinterpret_cast<const float*>(ws + (size_t)pu * REC_DW);
        // V-half: laundered pointer -> 11 wide vector loads (dwordx4)
        uint4 cv[11];
        ld_cv(cv, ws + (size_t)p * REC_DW);

        // gather 9 features for both rows (conflict-free: stride 1028 B)
        float xg0[K_IN], xg1[K_IN];
        #pragma unroll
        for (int k = 0; k < K_IN; ++k) {
            const int c = (int)cvdw(cv, k);
            xg0[k] = __builtin_amdgcn_cvt_f32_fp8((int)row0[c], 0);
            xg1[k] = __builtin_amdgcn_cvt_f32_fp8((int)row1[c], 0);
        }

        // layer 1: quantized accumulate (W1q from cv), 2 rows share dequant
        f32x2 H0[5], H1[5];
        #pragma unroll
        for (int j = 0; j < 5; ++j) { H0[j] = f32x2{0.f, 0.f}; H1[j] = f32x2{0.f, 0.f}; }
        #pragma unroll
        for (int k = 0; k < K_IN; ++k) {
            const f32x2 xa = {xg0[k], xg0[k]};
            const f32x2 xb = {xg1[k], xg1[k]};
            #pragma unroll
            for (int j = 0; j < 5; ++j) {
                const int t = k * 5 + j;
                const f32x2 w = unpk8s(cvdw(cv, 20 + (t >> 1)), t & 1);
                H0[j] = pkfma(xa, w, H0[j]);
                H1[j] = pkfma(xb, w, H1[j]);
            }
        }
        // z = H*s1C + b1C; r = 1/(exp2(z)+1)  (tanh = 1-2r folded into cw,c0)
        const float s1c = cvf(cv, 9);
        const f32x2 s1p = {s1c, s1c};
        f32x2 r0[5], r1[5];
        #pragma unroll
        for (int j = 0; j < 5; ++j) {
            const f32x2 bj = {cvf(cv, 10 + 2 * j), cvf(cv, 11 + 2 * j)};
            const f32x2 z0 = pkfma(H0[j], s1p, bj);
            const f32x2 z1 = pkfma(H1[j], s1p, bj);
            r0[j] = f32x2{sigm_r(z0[0]), sigm_r(z0[1])};
            r1[j] = f32x2{sigm_r(z1[0]), sigm_r(z1[1])};
        }

        // collapsed layers 2+3: y += c0 + sum_w cw[w]*r_w
        const float c0 = rfs[48];
        f32x2 A0 = {0.f, 0.f}, A1 = {0.f, 0.f};
        #pragma unroll
        for (int j = 0; j < 5; ++j) {
            const f32x2 cwj = {rfs[50 + 2 * j], rfs[51 + 2 * j]};
            A0 = pkfma(cwj, r0[j], A0);
            A1 = pkfma(cwj, r1[j], A1);
        }
        y0 += c0 + A0[0] + A0[1];
        y1 += c0 + A1[0] + A1[1];
    }

    partial[wave][lane]      = y0;
    partial[wave][lane + 64] = y1;
    __syncthreads();

    // ---- block reduction over the 16 waves + outputs ----
    if (tid < TB) {
        float s = 0.0f;
        #pragma unroll
        for (int w = 0; w < NWAVE; ++w) s += partial[w][tid];
        // two pgroup blocks contribute per y element; fp32 add is commutative
        atomicAdd(&out[b0 + tid], s);
    }

    if (blockIdx.y == 0 && tid < 64) {
        // channel 2: sum(|w_last|), computed redundantly per row-block
        float sa = 0.0f;
        #pragma unroll
        for (int i = 0; i < P_TOT / 64; ++i) sa += fabsf(wl[tid + 64 * i]);
        #pragma unroll
        for (int off = 32; off > 0; off >>= 1) sa += __shfl_down(sa, off);
        sa = __shfl(sa, 0);
        out[B_TOT + b0 + tid]      = sa;
        out[B_TOT + b0 + 64 + tid] = sa;
    }
}

extern "C" void kernel_launch(void* const* d_in, const int* in_sizes, int n_in,
                              void* d_out, int out_size, void* d_ws, size_t ws_size,
                              hipStream_t stream)
{
    const float* x  = (const float*)d_in[0];
    const int*   idx= (const int*)  d_in[1];
    const float* W1 = (const float*)d_in[2];
    const float* b1 = (const float*)d_in[3];
    const float* W2 = (const float*)d_in[4];
    const float* b2 = (const float*)d_in[5];
    const float* W3 = (const float*)d_in[6];
    const float* b3 = (const float*)d_in[7];
    const float* wl = (const float*)d_in[8];
    float* out = (float*)d_out;
    uint32_t* ws = (uint32_t*)d_ws;   // need 256KB; ws >= 950KB established in R10

    // zero the y channel (atomicAdd accumulates into it)
    (void)hipMemsetAsync(out, 0, B_TOT * sizeof(float), stream);

    prep_quant<<<P_TOT, 64, 0, stream>>>(idx, W1, b1, W2, b2, W3, b3, wl, ws);

    const int smem = TB * LSTR;  // 131584 B dynamic LDS (>64KB -> opt in)
    (void)hipFuncSetAttribute(reinterpret_cast<const void*>(dnn_q8),
                              hipFuncAttributeMaxDynamicSharedMemorySize, smem);

    dim3 grid(B_TOT / TB, PGRP);   // 128 x 2 = 256 blocks
    dnn_q8<<<grid, THREADS, smem, stream>>>(x, ws, wl, out);
}